// Round 9
// baseline (192.591 us; speedup 1.0000x reference)
//
#include <hip/hip_runtime.h>
#include <stdint.h>

// ---------------- problem constants (from reference) ----------------
constexpr int NN   = 20000;          // N_NODES
constexpr int DD   = 8;              // D
constexpr int ND   = NN * DD;        // 160000 block-rows
constexpr uint32_t HSIZE = 1u << 20; // 1,048,576 slots for 500k keys
constexpr uint32_t HMASK = HSIZE - 1;
// packed slot: (key << 19) | edge_idx.  key < 2^29, idx < 2^19. EMPTY = all-ones.
constexpr unsigned long long EMPTY64 = ~0ULL;

typedef float v4f __attribute__((ext_vector_type(4)));

__device__ __forceinline__ uint32_t hkey(uint32_t k) {
    k *= 2654435761u;
    return k ^ (k >> 15);
}

__device__ __forceinline__ int hprobe(const unsigned long long* __restrict__ slots,
                                      uint32_t key, int fallback) {
    uint32_t s = hkey(key) & HMASK;
    while (true) {
        unsigned long long v = slots[s];
        if (v == EMPTY64) return fallback;
        if ((uint32_t)(v >> 19) == key) return (int)(v & 0x7FFFFu);
        s = (s + 1) & HMASK;
    }
}

// 8x8 MAC: acc[k] += F_a[j][i] * F_b[j][k]  (P = A^T B, lane owns row i)
__device__ __forceinline__ void mac8(const float* __restrict__ fav,
                                     const float* __restrict__ fbv,
                                     int i, float* __restrict__ acc) {
#pragma unroll
    for (int j = 0; j < 8; ++j) {
        float  a  = fav[j * 8 + i];
        float4 b0 = *(const float4*)&fbv[j * 8];
        float4 b1 = *(const float4*)&fbv[j * 8 + 4];
        acc[0] = fmaf(a, b0.x, acc[0]);  acc[1] = fmaf(a, b0.y, acc[1]);
        acc[2] = fmaf(a, b0.z, acc[2]);  acc[3] = fmaf(a, b0.w, acc[3]);
        acc[4] = fmaf(a, b1.x, acc[4]);  acc[5] = fmaf(a, b1.y, acc[5]);
        acc[6] = fmaf(a, b1.z, acc[6]);  acc[7] = fmaf(a, b1.w, acc[7]);
    }
}

// ---------------- fill: slots=EMPTY (16B), deg=1, flags=0 -----------------
__global__ void k_fill(unsigned long long* __restrict__ slots,
                       float* __restrict__ deg, uint32_t* __restrict__ flags,
                       int nflag) {
    uint32_t i = blockIdx.x * blockDim.x + threadIdx.x;
    if (i < HSIZE / 2) {
        ulonglong2 v; v.x = EMPTY64; v.y = EMPTY64;
        ((ulonglong2*)slots)[i] = v;
    }
    if (i < (uint32_t)ND) deg[i] = 1.0f;
    if (i < (uint32_t)nflag) flags[i] = 0u;
}

// ---------------- insert + duplicate flagging -----------------------------
// Robin-Hood atomicMin64. Any same-key meeting flags BOTH edge indices:
// slots only decrease and empties are never created, so every duplicated
// key's copies all get flagged (incl. the min copy). Min-index semantics ==
// reference's stable argsort+searchsorted.
__global__ void k_insert(const int* __restrict__ row, const int* __restrict__ col,
                         unsigned long long* __restrict__ slots,
                         uint32_t* __restrict__ flags, int E) {
    int e = blockIdx.x * blockDim.x + threadIdx.x;
    if (e >= E) return;
    uint32_t key = (uint32_t)(row[e] * NN + col[e]);
    unsigned long long cur = ((unsigned long long)key << 19) | (unsigned)e;
    uint32_t s = hkey(key) & HMASK;
    while (true) {
        unsigned long long old = atomicMin(&slots[s], cur);
        if (old == EMPTY64) break;
        if ((uint32_t)(old >> 19) == key) {            // duplicate meeting
            int a = (int)(old & 0x7FFFFu), b = (int)(cur & 0x7FFFFu);
            atomicOr(&flags[a >> 5], 1u << (a & 31));
            atomicOr(&flags[b >> 5], 1u << (b & 31));
            break;                                      // min kept by atomicMin
        }
        if (old > cur) { cur = old; key = (uint32_t)(cur >> 19); }
        s = (s + 1) & HMASK;
    }
}

// ---------------- pass A: optimistic pair deg (no probes, no task) --------
// Pair p: P = F_p^T F_{p+EH}; rowsum|P| -> deg[row[p]], colsum -> deg[col[p]].
__global__ void __launch_bounds__(256)
k_pairdeg(const float* __restrict__ F, const int* __restrict__ row,
          const int* __restrict__ col, float* __restrict__ deg, int EH) {
    __shared__ float fa[64 * 68];
    __shared__ int s_row[32], s_col[32];
    const int t  = threadIdx.x;
    const int b0 = blockIdx.x * 32;
    const int np = min(32, EH - b0);

    if (t < 32 && t < np) { s_row[t] = row[b0 + t]; s_col[t] = col[b0 + t]; }
    const float4* F4 = (const float4*)F;
#pragma unroll
    for (int p = 0; p < 4; ++p) {
        int q = t + p * 256;                      // 0..1023
        int sl = q >> 4, sub = q & 15, pi = sl & 31;
        if (pi < np) {
            int x = b0 + pi + ((sl & 32) ? EH : 0);
            *(float4*)&fa[sl * 68 + (sub << 2)] = F4[(size_t)x * 16 + sub];
        }
    }
    __syncthreads();

    const int g = t >> 3, i = t & 7;
    if (g >= np) return;
    float acc[8] = {0,0,0,0,0,0,0,0};
    mac8(&fa[g * 68], &fa[(g + 32) * 68], i, acc);
    float b0f = fabsf(acc[0]), b1 = fabsf(acc[1]), b2 = fabsf(acc[2]), b3 = fabsf(acc[3]);
    float b4  = fabsf(acc[4]), b5 = fabsf(acc[5]), b6 = fabsf(acc[6]), b7 = fabsf(acc[7]);
    float rs  = b0f + b1 + b2 + b3 + b4 + b5 + b6 + b7;
    atomicAdd(&deg[s_row[g] * DD + i], rs);       // edge p row contribution
#pragma unroll
    for (int m = 1; m < 8; m <<= 1) {             // colsum = partner's rowsum
        b0f += __shfl_xor(b0f, m); b1 += __shfl_xor(b1, m);
        b2  += __shfl_xor(b2, m);  b3 += __shfl_xor(b3, m);
        b4  += __shfl_xor(b4, m);  b5 += __shfl_xor(b5, m);
        b6  += __shfl_xor(b6, m);  b7 += __shfl_xor(b7, m);
    }
    float ci = (i & 4) ? ((i & 2) ? ((i & 1) ? b7 : b6) : ((i & 1) ? b5 : b4))
                       : ((i & 2) ? ((i & 1) ? b3 : b2) : ((i & 1) ? b1 : b0f));
    atomicAdd(&deg[s_col[g] * DD + i], ci);       // edge p+EH row contribution
}

// ---------------- repair deg for dup-affected edges (~hundreds) -----------
// Edge e's true rev may differ from partner iff partner's key is duplicated.
__global__ void k_fixdeg(const float* __restrict__ F, const int* __restrict__ row,
                         const int* __restrict__ col,
                         const unsigned long long* __restrict__ slots,
                         const uint32_t* __restrict__ flags,
                         float* __restrict__ deg, int E, int EH) {
    int e = blockIdx.x * blockDim.x + threadIdx.x;
    if (e >= E) return;
    bool tail = (e == 2 * EH);                    // odd-E safety (never for even E)
    int partner = tail ? e : ((e < EH) ? e + EH : e - EH);
    if (!tail && !((flags[partner >> 5] >> (partner & 31)) & 1u)) return;
    int r = row[e], c = col[e];
    int f = hprobe(slots, (uint32_t)(c * NN + r), e);
    if (!tail && f == partner) return;            // optimistic was right
    const float* Fe = F + (size_t)e * 64;
    const float* Ff = F + (size_t)f * 64;
    const float* Fp = F + (size_t)partner * 64;
    for (int i = 0; i < 8; ++i) {
        float s1 = 0.f, s2 = 0.f;
        for (int k = 0; k < 8; ++k) {
            float p1 = 0.f, p2 = 0.f;
            for (int j = 0; j < 8; ++j) {
                float a = Fe[j * 8 + i];
                p1 = fmaf(a, Ff[j * 8 + k], p1);
                p2 = fmaf(a, Fp[j * 8 + k], p2);
            }
            s1 += fabsf(p1); s2 += fabsf(p2);
        }
        atomicAdd(&deg[r * DD + i], tail ? s1 : (s1 - s2));
    }
}

// ---------------- dinv = deg^-0.5 AND diagonal blocks of out --------------
__global__ void k_dinv_diag(const float* __restrict__ deg, float* __restrict__ dinv,
                            float* __restrict__ out, int E) {
    int r = blockIdx.x * blockDim.x + threadIdx.x;
    if (r >= ND) return;
    float dv = 1.0f / sqrtf(deg[r]);
    dinv[r] = dv;
    float dd = dv * dv;
    int i = r & 7;
    v4f a = { 0.f, 0.f, 0.f, 0.f };
    v4f b = { 0.f, 0.f, 0.f, 0.f };
    if (i < 4) a[i] = dd; else b[i - 4] = dd;
    size_t base = (size_t)E * 64 + (size_t)(r >> 3) * 64 + (size_t)i * 8;
    __builtin_nontemporal_store(a, (v4f*)&out[base]);
    __builtin_nontemporal_store(b, (v4f*)&out[base + 4]);
}

// ---------------- pass B: optimistic pair normalize+write -----------------
__global__ void __launch_bounds__(256)
k_pnormP(const float* __restrict__ F, const int* __restrict__ row,
         const int* __restrict__ col, const float* __restrict__ dinv,
         float* __restrict__ out, int EH) {
    __shared__ float fa[64 * 68];
    __shared__ int s_row[32], s_col[32];
    const int t  = threadIdx.x;
    const int b0 = blockIdx.x * 32;
    const int np = min(32, EH - b0);

    if (t < 32 && t < np) { s_row[t] = row[b0 + t]; s_col[t] = col[b0 + t]; }
    const float4* F4 = (const float4*)F;
#pragma unroll
    for (int p = 0; p < 4; ++p) {
        int q = t + p * 256;
        int sl = q >> 4, sub = q & 15, pi = sl & 31;
        if (pi < np) {
            int x = b0 + pi + ((sl & 32) ? EH : 0);
            *(float4*)&fa[sl * 68 + (sub << 2)] = F4[(size_t)x * 16 + sub];
        }
    }
    __syncthreads();

    const int g = t >> 3, i = t & 7;
    if (g >= np) return;
    const int e = b0 + g, qe = e + EH;
    float acc[8] = {0,0,0,0,0,0,0,0};
    mac8(&fa[g * 68], &fa[(g + 32) * 68], i, acc);

    const int r = s_row[g], c = s_col[g];
    float dr = dinv[r * DD + i];
    v4f dc0 = *(const v4f*)&dinv[c * DD];
    v4f dc1 = *(const v4f*)&dinv[c * DD + 4];

    float v[8];
    v[0] = acc[0] * dr * dc0.x;  v[1] = acc[1] * dr * dc0.y;
    v[2] = acc[2] * dr * dc0.z;  v[3] = acc[3] * dr * dc0.w;
    v[4] = acc[4] * dr * dc1.x;  v[5] = acc[5] * dr * dc1.y;
    v[6] = acc[6] * dr * dc1.z;  v[7] = acc[7] * dr * dc1.w;

    v4f w0 = { v[0], v[1], v[2], v[3] };
    v4f w1 = { v[4], v[5], v[6], v[7] };
    size_t ob = (size_t)e * 64 + i * 8;
    __builtin_nontemporal_store(w0, (v4f*)&out[ob]);
    __builtin_nontemporal_store(w1, (v4f*)&out[ob + 4]);

    // out[partner] = transpose (normalization symmetric, P_q = P_e^T exact)
#pragma unroll
    for (int m = 1; m < 8; m <<= 1) {
#pragma unroll
        for (int j = 0; j < 8; ++j) {
            if ((j & m) == 0) {
                float sel = (i & m) ? v[j] : v[j | m];
                float got = __shfl_xor(sel, m);
                float nj  = (i & m) ? got : v[j];
                float njm = (i & m) ? v[j | m] : got;
                v[j] = nj;  v[j | m] = njm;
            }
        }
    }
    v4f u0 = { v[0], v[1], v[2], v[3] };
    v4f u1 = { v[4], v[5], v[6], v[7] };
    size_t qb = (size_t)qe * 64 + i * 8;
    __builtin_nontemporal_store(u0, (v4f*)&out[qb]);
    __builtin_nontemporal_store(u1, (v4f*)&out[qb + 4]);
}

// ---------------- repair out for dup-affected edges (exact recompute) -----
__global__ void k_fixout(const float* __restrict__ F, const int* __restrict__ row,
                         const int* __restrict__ col,
                         const unsigned long long* __restrict__ slots,
                         const uint32_t* __restrict__ flags,
                         const float* __restrict__ dinv, float* __restrict__ out,
                         int E, int EH) {
    int e = blockIdx.x * blockDim.x + threadIdx.x;
    if (e >= E) return;
    bool tail = (e == 2 * EH);
    int partner = tail ? e : ((e < EH) ? e + EH : e - EH);
    if (!tail && !((flags[partner >> 5] >> (partner & 31)) & 1u)) return;
    int r = row[e], c = col[e];
    int f = hprobe(slots, (uint32_t)(c * NN + r), e);
    const float* Fe = F + (size_t)e * 64;
    const float* Ff = F + (size_t)f * 64;
    for (int i = 0; i < 8; ++i) {
        float dr = dinv[r * DD + i];
        for (int k = 0; k < 8; ++k) {
            float p = 0.f;
            for (int j = 0; j < 8; ++j)
                p = fmaf(Fe[j * 8 + i], Ff[j * 8 + k], p);
            out[(size_t)e * 64 + i * 8 + k] = p * dr * dinv[c * DD + k];
        }
    }
}

extern "C" void kernel_launch(void* const* d_in, const int* in_sizes, int n_in,
                              void* d_out, int out_size, void* d_ws, size_t ws_size,
                              hipStream_t stream) {
    const float* F  = (const float*)d_in[0];
    const int*   ei = (const int*)d_in[1];
    const int E = in_sizes[1] / 2;
    const int* row = ei;
    const int* col = ei + E;
    const int EH = E / 2;
    const int NB = (EH + 31) / 32;
    const int nflag = (E + 31) / 32;

    // workspace layout (~9.6 MB)
    unsigned long long* slots = (unsigned long long*)d_ws;          // 8 MB
    uint32_t* flags = (uint32_t*)(slots + HSIZE);                   // ~64 KB
    float*    deg   = (float*)(flags + nflag);
    float*    dinv  = deg + ND;
    float*    out   = (float*)d_out;

    k_fill     <<<(HSIZE / 2 + 255) / 256, 256, 0, stream>>>(slots, deg, flags, nflag);
    k_insert   <<<(E + 255) / 256,  256, 0, stream>>>(row, col, slots, flags, E);
    k_pairdeg  <<<NB,               256, 0, stream>>>(F, row, col, deg, EH);
    k_fixdeg   <<<(E + 255) / 256,  256, 0, stream>>>(F, row, col, slots, flags, deg, E, EH);
    k_dinv_diag<<<(ND + 255) / 256, 256, 0, stream>>>(deg, dinv, out, E);
    k_pnormP   <<<NB,               256, 0, stream>>>(F, row, col, dinv, out, EH);
    k_fixout   <<<(E + 255) / 256,  256, 0, stream>>>(F, row, col, slots, flags, dinv, out, E, EH);
}

// Round 10
// 155.143 us; speedup vs baseline: 1.2414x; 1.2414x over previous
//
#include <hip/hip_runtime.h>
#include <stdint.h>

// ---------------- problem constants (from reference) ----------------
constexpr int NN   = 20000;          // N_NODES
constexpr int DD   = 8;              // D
constexpr int ND   = NN * DD;        // 160000 block-rows
constexpr uint32_t HSIZE = 1u << 20; // 1,048,576 slots for 500k keys
constexpr uint32_t HMASK = HSIZE - 1;
// packed slot: (key << 19) | edge_idx.  key < 2^29, idx < 2^19. EMPTY = all-ones.
constexpr unsigned long long EMPTY64 = ~0ULL;

typedef float v4f __attribute__((ext_vector_type(4)));

__device__ __forceinline__ uint32_t hkey(uint32_t k) {
    k *= 2654435761u;
    return k ^ (k >> 15);
}

__device__ __forceinline__ int hprobe(const unsigned long long* __restrict__ slots,
                                      uint32_t key, int fallback) {
    uint32_t s = hkey(key) & HMASK;
    while (true) {
        unsigned long long v = slots[s];
        if (v == EMPTY64) return fallback;
        if ((uint32_t)(v >> 19) == key) return (int)(v & 0x7FFFFu);
        s = (s + 1) & HMASK;
    }
}

// 8x8 MAC: acc[k] += F_a[j][i] * F_b[j][k]  (P = A^T B, lane owns row i)
__device__ __forceinline__ void mac8(const float* __restrict__ fav,
                                     const float* __restrict__ fbv,
                                     int i, float* __restrict__ acc) {
#pragma unroll
    for (int j = 0; j < 8; ++j) {
        float  a  = fav[j * 8 + i];
        float4 b0 = *(const float4*)&fbv[j * 8];
        float4 b1 = *(const float4*)&fbv[j * 8 + 4];
        acc[0] = fmaf(a, b0.x, acc[0]);  acc[1] = fmaf(a, b0.y, acc[1]);
        acc[2] = fmaf(a, b0.z, acc[2]);  acc[3] = fmaf(a, b0.w, acc[3]);
        acc[4] = fmaf(a, b1.x, acc[4]);  acc[5] = fmaf(a, b1.y, acc[5]);
        acc[6] = fmaf(a, b1.z, acc[6]);  acc[7] = fmaf(a, b1.w, acc[7]);
    }
}

// ---------------- fill: slots=EMPTY (16B), deg=1, flags=0 -----------------
__global__ void k_fill(unsigned long long* __restrict__ slots,
                       float* __restrict__ deg, uint32_t* __restrict__ flags,
                       int nflag) {
    uint32_t i = blockIdx.x * blockDim.x + threadIdx.x;
    if (i < HSIZE / 2) {
        ulonglong2 v; v.x = EMPTY64; v.y = EMPTY64;
        ((ulonglong2*)slots)[i] = v;
    }
    if (i < (uint32_t)ND) deg[i] = 1.0f;
    if (i < (uint32_t)nflag) flags[i] = 0u;
}

// ---------------- insert + duplicate flagging (validated in R9) -----------
// Robin-Hood atomicMin64; any same-key meeting flags both edge indices.
// Slots only decrease and never become empty once filled, so every copy of
// a duplicated key participates in a meeting -> flag set covers all dups.
__global__ void k_insert(const int* __restrict__ row, const int* __restrict__ col,
                         unsigned long long* __restrict__ slots,
                         uint32_t* __restrict__ flags, int E) {
    int e = blockIdx.x * blockDim.x + threadIdx.x;
    if (e >= E) return;
    uint32_t key = (uint32_t)(row[e] * NN + col[e]);
    unsigned long long cur = ((unsigned long long)key << 19) | (unsigned)e;
    uint32_t s = hkey(key) & HMASK;
    while (true) {
        unsigned long long old = atomicMin(&slots[s], cur);
        if (old == EMPTY64) break;
        if ((uint32_t)(old >> 19) == key) {            // duplicate meeting
            int a = (int)(old & 0x7FFFFu), b = (int)(cur & 0x7FFFFu);
            atomicOr(&flags[a >> 5], 1u << (a & 31));
            atomicOr(&flags[b >> 5], 1u << (b & 31));
            break;
        }
        if (old > cur) { cur = old; key = (uint32_t)(cur >> 19); }
        s = (s + 1) & HMASK;
    }
}

// ---------------- pass A: flag-gated classify + deg accumulation ----------
// Block covers edges [b0,b0+32) of first half and [EH+b0,EH+b0+32) of the
// second. Clean (unflagged) pair: rev[x]=partner, me=x -> no probes at all.
// Flagged edges (~hundreds, incl. self-loops) take the exact probe path.
__global__ void __launch_bounds__(256)
k_deg(const float* __restrict__ F,
      const int* __restrict__ row, const int* __restrict__ col,
      const unsigned long long* __restrict__ slots,
      const uint32_t* __restrict__ flags, int* __restrict__ task,
      float* __restrict__ deg, int E, int EH) {
    __shared__ float fa[64 * 68];
    __shared__ int s_x[64], s_f[64], s_cls[64], s_row[64], s_col[64], s_fl[64];
    const int t  = threadIdx.x;
    const int b0 = blockIdx.x * 32;

    if (t < 64) {
        int s = t;
        int x = (s < 32) ? (b0 + s) : (EH + b0 + (s - 32));
        bool valid = (s < 32) ? (x < EH) : (x < E);
        int r = 0, c = 0, fl = 1;
        if (valid) {
            r = row[x]; c = col[x];
            int p = (s < 32) ? x + EH : x - EH;           // partner edge index
            fl = (int)(((flags[x >> 5] >> (x & 31)) |
                        (flags[p >> 5] >> (p & 31))) & 1u);
        } else x = -1;
        s_x[s] = x; s_row[s] = r; s_col[s] = c; s_fl[s] = fl;
    }
    __syncthreads();

    if (t < 64) {
        int s = t, x = s_x[s];
        int cls = 0, f = 0;
        if (x >= 0) {
            int q = s ^ 32, qx = s_x[q];
            int r = s_row[s], c = s_col[s];
            if (!s_fl[s] && qx >= 0 && s_row[q] == c && s_col[q] == r) {
                f = qx;                                   // rev = partner, me = x
                cls = (x < f) ? 2 : 0;
            } else {                                      // exact fallback (rare)
                f = hprobe(slots, (uint32_t)(c * NN + r), x);
                int me = hprobe(slots, (uint32_t)(r * NN + c), x);
                cls = (f == x) ? 1 : ((me == x) ? ((x < f) ? 2 : 0) : 1);
            }
            task[x] = f | (cls << 29);
        }
        s_f[s] = f; s_cls[s] = cls;
    }

    // stage all 64 slots' F blocks (sequential, coalesced)
    const float4* F4 = (const float4*)F;
#pragma unroll
    for (int p = 0; p < 4; ++p) {
        int q = t + p * 256;                     // 0..1023
        int sl = q >> 4, sub = q & 15;
        int x = s_x[sl];
        if (x >= 0)
            *(float4*)&fa[sl * 68 + (sub << 2)] = F4[(size_t)x * 16 + sub];
    }
    __syncthreads();

    const int g = t >> 3, i = t & 7;
#pragma unroll
    for (int item = 0; item < 2; ++item) {
        int s = (item == 0) ? g : (g + 32);
        int q = s ^ 32;
        int x = s_x[s];
        int cls = (x >= 0) ? s_cls[s] : 0;
        if (cls) {
            int f = s_f[s];
            const float* fav = &fa[s * 68];
            float acc[8] = {0,0,0,0,0,0,0,0};
            const float* lsrc = (f == s_x[q]) ? &fa[q * 68] : ((f == x) ? fav : nullptr);
            if (lsrc) mac8(fav, lsrc, i, acc);
            else      mac8(fav, F + (size_t)f * 64, i, acc);   // rare (dups)
            float b0f=fabsf(acc[0]),b1=fabsf(acc[1]),b2=fabsf(acc[2]),b3=fabsf(acc[3]);
            float b4=fabsf(acc[4]),b5=fabsf(acc[5]),b6=fabsf(acc[6]),b7=fabsf(acc[7]);
            atomicAdd(&deg[s_row[s] * DD + i], b0f+b1+b2+b3+b4+b5+b6+b7);
            if (cls == 2) {        // partner rowsum = our colsum (P_f = P_e^T)
#pragma unroll
                for (int m = 1; m < 8; m <<= 1) {
                    b0f+=__shfl_xor(b0f,m); b1+=__shfl_xor(b1,m);
                    b2 +=__shfl_xor(b2,m);  b3+=__shfl_xor(b3,m);
                    b4 +=__shfl_xor(b4,m);  b5+=__shfl_xor(b5,m);
                    b6 +=__shfl_xor(b6,m);  b7+=__shfl_xor(b7,m);
                }
                float ci = (i&4) ? ((i&2)?((i&1)?b7:b6):((i&1)?b5:b4))
                                 : ((i&2)?((i&1)?b3:b2):((i&1)?b1:b0f));
                atomicAdd(&deg[s_col[s] * DD + i], ci);
            }
        }
    }
}

// ---------------- dinv = deg^-0.5 AND diagonal blocks of out --------------
__global__ void k_dinv_diag(const float* __restrict__ deg, float* __restrict__ dinv,
                            float* __restrict__ out, int E) {
    int r = blockIdx.x * blockDim.x + threadIdx.x;
    if (r >= ND) return;
    float dv = 1.0f / sqrtf(deg[r]);
    dinv[r] = dv;
    float dd = dv * dv;
    int i = r & 7;
    v4f a = { 0.f, 0.f, 0.f, 0.f };
    v4f b = { 0.f, 0.f, 0.f, 0.f };
    if (i < 4) a[i] = dd; else b[i - 4] = dd;
    size_t base = (size_t)E * 64 + (size_t)(r >> 3) * 64 + (size_t)i * 8;
    __builtin_nontemporal_store(a, (v4f*)&out[base]);
    __builtin_nontemporal_store(b, (v4f*)&out[base + 4]);
}

// ---------------- pass B: recompute P (pair-staged), normalize, write -----
__global__ void __launch_bounds__(256)
k_pnorm(const float* __restrict__ F,
        const int* __restrict__ row, const int* __restrict__ col,
        const int* __restrict__ task, const float* __restrict__ dinv,
        float* __restrict__ out, int E, int EH) {
    __shared__ float fa[64 * 68];
    __shared__ int s_x[64], s_f[64], s_cls[64], s_row[64], s_col[64];
    const int t  = threadIdx.x;
    const int b0 = blockIdx.x * 32;

    if (t < 64) {
        int s = t;
        int x = (s < 32) ? (b0 + s) : (EH + b0 + (s - 32));
        bool valid = (s < 32) ? (x < EH) : (x < E);
        int cls = 0, f = 0, r = 0, c = 0;
        if (valid) {
            int w = task[x];
            cls = w >> 29;
            f   = w & ((1 << 29) - 1);
            r = row[x]; c = col[x];
        } else x = -1;
        s_x[s] = x; s_f[s] = f; s_cls[s] = cls; s_row[s] = r; s_col[s] = c;
    }
    __syncthreads();

    const float4* F4 = (const float4*)F;
#pragma unroll
    for (int p = 0; p < 4; ++p) {
        int q = t + p * 256;
        int sl = q >> 4, sub = q & 15;
        int x = s_x[sl];
        if (x >= 0)
            *(float4*)&fa[sl * 68 + (sub << 2)] = F4[(size_t)x * 16 + sub];
    }
    __syncthreads();

    const int g = t >> 3, i = t & 7;
#pragma unroll
    for (int item = 0; item < 2; ++item) {
        int s = (item == 0) ? g : (g + 32);
        int q = s ^ 32;
        int x = s_x[s];
        int cls = (x >= 0) ? s_cls[s] : 0;
        if (cls) {
            int f = s_f[s];
            const float* fav = &fa[s * 68];
            float acc[8] = {0,0,0,0,0,0,0,0};
            const float* lsrc = (f == s_x[q]) ? &fa[q * 68] : ((f == x) ? fav : nullptr);
            if (lsrc) mac8(fav, lsrc, i, acc);
            else      mac8(fav, F + (size_t)f * 64, i, acc);

            const int r = s_row[s], c = s_col[s];
            float dr = dinv[r * DD + i];
            v4f dc0 = *(const v4f*)&dinv[c * DD];
            v4f dc1 = *(const v4f*)&dinv[c * DD + 4];

            float v[8];
            v[0]=acc[0]*dr*dc0.x; v[1]=acc[1]*dr*dc0.y;
            v[2]=acc[2]*dr*dc0.z; v[3]=acc[3]*dr*dc0.w;
            v[4]=acc[4]*dr*dc1.x; v[5]=acc[5]*dr*dc1.y;
            v[6]=acc[6]*dr*dc1.z; v[7]=acc[7]*dr*dc1.w;

            v4f w0 = { v[0], v[1], v[2], v[3] };
            v4f w1 = { v[4], v[5], v[6], v[7] };
            size_t ob = (size_t)x * 64 + i * 8;
            __builtin_nontemporal_store(w0, (v4f*)&out[ob]);
            __builtin_nontemporal_store(w1, (v4f*)&out[ob + 4]);

            if (cls == 2) {
                // out[f] = transpose(out[x]) (normalization symmetric).
#pragma unroll
                for (int m = 1; m < 8; m <<= 1) {
#pragma unroll
                    for (int j = 0; j < 8; ++j) {
                        if ((j & m) == 0) {
                            float sel = (i & m) ? v[j] : v[j | m];
                            float got = __shfl_xor(sel, m);
                            float nj  = (i & m) ? got : v[j];
                            float njm = (i & m) ? v[j | m] : got;
                            v[j] = nj;  v[j | m] = njm;
                        }
                    }
                }
                v4f u0 = { v[0], v[1], v[2], v[3] };
                v4f u1 = { v[4], v[5], v[6], v[7] };
                size_t fb_ = (size_t)f * 64 + i * 8;
                __builtin_nontemporal_store(u0, (v4f*)&out[fb_]);
                __builtin_nontemporal_store(u1, (v4f*)&out[fb_ + 4]);
            }
        }
    }
}

extern "C" void kernel_launch(void* const* d_in, const int* in_sizes, int n_in,
                              void* d_out, int out_size, void* d_ws, size_t ws_size,
                              hipStream_t stream) {
    const float* F  = (const float*)d_in[0];
    const int*   ei = (const int*)d_in[1];
    const int E = in_sizes[1] / 2;
    const int* row = ei;
    const int* col = ei + E;
    const int EH = E / 2;
    const int NB = ((E - EH) + 31) / 32;      // pair-block grid
    const int nflag = (E + 31) / 32;

    // workspace layout (~11.9 MB)
    unsigned long long* slots = (unsigned long long*)d_ws;          // 8 MB
    uint32_t* flags = (uint32_t*)(slots + HSIZE);                   // ~64 KB
    int*      task  = (int*)(flags + nflag);
    float*    deg   = (float*)(task + E);
    float*    dinv  = deg + ND;
    float*    out   = (float*)d_out;

    k_fill     <<<(HSIZE / 2 + 255) / 256, 256, 0, stream>>>(slots, deg, flags, nflag);
    k_insert   <<<(E + 255) / 256,  256, 0, stream>>>(row, col, slots, flags, E);
    k_deg      <<<NB,               256, 0, stream>>>(F, row, col, slots, flags, task, deg, E, EH);
    k_dinv_diag<<<(ND + 255) / 256, 256, 0, stream>>>(deg, dinv, out, E);
    k_pnorm    <<<NB,               256, 0, stream>>>(F, row, col, task, dinv, out, E, EH);
}